// Round 16
// baseline (274.628 us; speedup 1.0000x reference)
//
#include <hip/hip_runtime.h>
#include <hip/hip_bf16.h>
#include <stdint.h>

// Problem constants
#define B_   512
#define T_   87
#define C_   512
#define H_   8
#define D_   64
#define BT_  44544        // B_*T_
#define BH_  4096         // B_*H_

typedef __attribute__((ext_vector_type(4))) float f32x4;
typedef __attribute__((ext_vector_type(8))) __bf16 bf16x8;
typedef __attribute__((ext_vector_type(4))) unsigned short u16x4;

__device__ __forceinline__ int mod29(int x) {
  return x < 29 ? x : (x < 58 ? x - 29 : x - 58);
}

// ---------------- converts ----------------

__global__ void convert_x_kernel(const float* __restrict__ x,
                                 __hip_bfloat16* __restrict__ xb, int n4) {
  int stride = gridDim.x * blockDim.x;
  for (int i = blockIdx.x * blockDim.x + threadIdx.x; i < n4; i += stride) {
    f32x4 v = ((const f32x4*)x)[i];
    u16x4 o;
    o.x = __builtin_bit_cast(unsigned short, __float2bfloat16(v.x));
    o.y = __builtin_bit_cast(unsigned short, __float2bfloat16(v.y));
    o.z = __builtin_bit_cast(unsigned short, __float2bfloat16(v.z));
    o.w = __builtin_bit_cast(unsigned short, __float2bfloat16(v.w));
    ((u16x4*)xb)[i] = o;
  }
}

__global__ void convert_w_kernel(const float* __restrict__ Wq, const float* __restrict__ Wk,
                                 const float* __restrict__ Wv, const float* __restrict__ Wp,
                                 const float* __restrict__ bq, const float* __restrict__ bk,
                                 const float* __restrict__ bv,
                                 __hip_bfloat16* __restrict__ wqkv,
                                 __hip_bfloat16* __restrict__ wp,
                                 float* __restrict__ biasc) {
  const int NW = 262144;                 // 512*512
  const int total = 3 * NW + NW + 1536;
  int stride = gridDim.x * blockDim.x;
  for (int i = blockIdx.x * blockDim.x + threadIdx.x; i < total; i += stride) {
    if (i < 3 * NW) {
      float v = (i < NW) ? Wq[i] : (i < 2 * NW ? Wk[i - NW] : Wv[i - 2 * NW]);
      wqkv[i] = __float2bfloat16(v);
    } else if (i < 4 * NW) {
      wp[i - 3 * NW] = __float2bfloat16(Wp[i - 3 * NW]);
    } else {
      int j = i - 4 * NW;
      biasc[j] = (j < 512) ? bq[j] : (j < 1024 ? bk[j - 512] : bv[j - 1024]);
    }
  }
}

// ---------------- gemmk: 256x128 tile, BK=32, 4 waves, per-wave 128x64 -------
// LDS: 2 bufs x (A 256x64B = 16KB + B 128x64B = 8KB) = 48KB -> 2 blocks/CU.
// 64B rows = 4 x 16B chunks; chunk s of row r holds global chunk s^((r>>1)&3)
// (R5/R8-verified swizzle -> 2-way bank aliasing only).
// Depth-1 reg staging (R7-verified): load kt+1 to regs, compute kt, write, sync.

// EPI 0: qkv row-major outputs (o0=q,o1=k,o2=v, bias=biasc). EPI 1: proj fp32.
template<int EPI>
__global__ __launch_bounds__(256) void gemmk_kernel(
    const __hip_bfloat16* __restrict__ A, const __hip_bfloat16* __restrict__ Bt,
    const float* __restrict__ bias, int ntn,
    void* __restrict__ o0, void* __restrict__ o1, void* __restrict__ o2) {
  constexpr int BUFB = 24576;            // A 16KB + B 8KB
  constexpr int BOFF = 16384;
  __shared__ __align__(16) char smem[2 * BUFB];

  int tid = threadIdx.x, lane = tid & 63, wave = tid >> 6;
  int r16 = lane & 15, r4 = lane >> 4;

  int nwg = gridDim.x;
  int wg = (blockIdx.x & 7) * (nwg >> 3) + (blockIdx.x >> 3);
  int tileM = (wg / ntn) * 256, tileN = (wg % ntn) * 128;

  int wr = wave >> 1, wc = wave & 1;     // 2M x 2N; per-wave 128 x 64
  int wbM = wr * 128, wbN = wc * 64;

  // staging geometry: thread covers A rows rb+64j (j=0..3), B rows rb+64j
  // (j=0..1), 16B chunk cc. Swizzled chunk slot constant across j (64|j-step).
  const int rb = tid >> 2, cc = tid & 3;
  const int csA = ((cc ^ ((rb >> 1) & 3)) << 4);
  const char* AgBase = (const char*)A + (size_t)(tileM + rb) * 1024 + cc * 16;
  const char* BgBase = (const char*)Bt + (size_t)(tileN + rb) * 1024 + cc * 16;

  f32x4 acc[8][4] = {};
  bf16x8 sA[4], sB[2];

  // ds_read row constants
  int arow[8], brow[4];
#pragma unroll
  for (int fm = 0; fm < 8; ++fm) arow[fm] = wbM + fm * 16 + r16;
#pragma unroll
  for (int fn = 0; fn < 4; ++fn) brow[fn] = wbN + fn * 16 + r16;

  // prologue: tile 0 -> regs -> LDS buf0
#pragma unroll
  for (int j = 0; j < 4; ++j) sA[j] = *(const bf16x8*)(AgBase + (size_t)j * 65536);
#pragma unroll
  for (int j = 0; j < 2; ++j) sB[j] = *(const bf16x8*)(BgBase + (size_t)j * 65536);
#pragma unroll
  for (int j = 0; j < 4; ++j)
    *(bf16x8*)(smem + (rb + 64 * j) * 64 + csA) = sA[j];
#pragma unroll
  for (int j = 0; j < 2; ++j)
    *(bf16x8*)(smem + BOFF + (rb + 64 * j) * 64 + csA) = sB[j];
  __syncthreads();

#pragma unroll
  for (int kt = 0; kt < 16; ++kt) {
    const int cur = kt & 1;
    if (kt < 15) {
#pragma unroll
      for (int j = 0; j < 4; ++j)
        sA[j] = *(const bf16x8*)(AgBase + (size_t)j * 65536 + (kt + 1) * 64);
#pragma unroll
      for (int j = 0; j < 2; ++j)
        sB[j] = *(const bf16x8*)(BgBase + (size_t)j * 65536 + (kt + 1) * 64);
    }
    {
      const char* Ab = smem + cur * BUFB;
      const char* Bb = Ab + BOFF;
      bf16x8 bfr[4];
#pragma unroll
      for (int fn = 0; fn < 4; ++fn)
        bfr[fn] = *(const bf16x8*)(Bb + brow[fn] * 64 +
                                   ((r4 ^ ((brow[fn] >> 1) & 3)) << 4));
      __builtin_amdgcn_s_setprio(1);
#pragma unroll
      for (int fm = 0; fm < 8; ++fm) {
        bf16x8 a = *(const bf16x8*)(Ab + arow[fm] * 64 +
                                    ((r4 ^ ((arow[fm] >> 1) & 3)) << 4));
#pragma unroll
        for (int fn = 0; fn < 4; ++fn)
          acc[fm][fn] = __builtin_amdgcn_mfma_f32_16x16x32_bf16(a, bfr[fn],
                                                                acc[fm][fn], 0, 0, 0);
      }
      __builtin_amdgcn_s_setprio(0);
    }
    if (kt < 15) {
      char* nb = smem + (cur ^ 1) * BUFB;
#pragma unroll
      for (int j = 0; j < 4; ++j)
        *(bf16x8*)(nb + (rb + 64 * j) * 64 + csA) = sA[j];
#pragma unroll
      for (int j = 0; j < 2; ++j)
        *(bf16x8*)(nb + BOFF + (rb + 64 * j) * 64 + csA) = sB[j];
    }
    __syncthreads();
  }

  // ---- bounce epilogue (R10-verified): frag -> LDS scratch -> coalesced ----
  if constexpr (EPI == 0) {
    char* scratch = smem + wave * 2304;                // 16 rows x 144B
    int gn0 = tileN + wbN;                             // head-aligned (64 | gn0)
    int sel = gn0 >> 9;                                // 0=q 1=k 2=v
    int hh = (gn0 & 511) >> 6;
    __hip_bfloat16* obase = (sel == 0) ? (__hip_bfloat16*)o0
                          : (sel == 1) ? (__hip_bfloat16*)o1 : (__hip_bfloat16*)o2;
#pragma unroll
    for (int fm = 0; fm < 8; ++fm) {
#pragma unroll
      for (int fn = 0; fn < 4; ++fn) {
        float bv = bias[gn0 + fn * 16 + r16];
#pragma unroll
        for (int rr = 0; rr < 4; ++rr)
          *(__hip_bfloat16*)(scratch + (r4 * 4 + rr) * 144 + (fn * 16 + r16) * 2) =
              __float2bfloat16(acc[fm][fn][rr] + bv);
      }
#pragma unroll
      for (int p = 0; p < 2; ++p) {
        bf16x8 vrow = *(const bf16x8*)(scratch + (p * 8 + (lane >> 3)) * 144 + (lane & 7) * 16);
        int gm = tileM + wbM + fm * 16 + p * 8 + (lane >> 3);
        int bb = gm / 87, tt = gm - bb * 87;
        *(bf16x8*)(obase + ((size_t)(bb * 8 + hh) * 96 + tt) * 64 + (lane & 7) * 8) = vrow;
      }
    }
  } else {
    char* scratch = smem + wave * 4352;                // 16 rows x 272B
#pragma unroll
    for (int fm = 0; fm < 8; ++fm) {
#pragma unroll
      for (int fn = 0; fn < 4; ++fn) {
        float bv = bias[tileN + wbN + fn * 16 + r16];
#pragma unroll
        for (int rr = 0; rr < 4; ++rr)
          *(float*)(scratch + (r4 * 4 + rr) * 272 + (fn * 16 + r16) * 4) =
              acc[fm][fn][rr] + bv;
      }
#pragma unroll
      for (int p = 0; p < 4; ++p) {
        f32x4 vr = *(const f32x4*)(scratch + (p * 4 + (lane >> 4)) * 272 + (lane & 15) * 16);
        int gm = tileM + wbM + fm * 16 + p * 4 + (lane >> 4);
        *(f32x4*)((float*)o0 + (size_t)gm * 512 + tileN + wbN + (lane & 15) * 4) = vr;
      }
    }
  }
}

// ---------------- attention per (b,h) (R12-verified, y-bounce) ---------------
#define QS_O  0
#define KS_O  13824
#define VT_O  27648
#define PB_O  40960

__global__ __launch_bounds__(256) void attn_kernel(
    const __hip_bfloat16* __restrict__ q_ws, const __hip_bfloat16* __restrict__ k_ws,
    const __hip_bfloat16* __restrict__ v_ws, __hip_bfloat16* __restrict__ y_ws) {
  __shared__ __align__(16) char smem[60928];

  int tid = threadIdx.x, lane = tid & 63, wave = tid >> 6;
  int bh = blockIdx.x, b = bh >> 3, h = bh & 7;
  int r16 = lane & 15, r4 = lane >> 4;

  {
    const bf16x8* gq = (const bf16x8*)(q_ws + (size_t)bh * 6144);
    const bf16x8* gk = (const bf16x8*)(k_ws + (size_t)bh * 6144);
    const bf16x8* gv = (const bf16x8*)(v_ws + (size_t)bh * 6144);
    for (int i = tid; i < 768; i += 256) {
      int row = i >> 3, ch = i & 7;
      *(bf16x8*)(smem + QS_O + row * 144 + ch * 16) = gq[i];
      *(bf16x8*)(smem + KS_O + row * 144 + ch * 16) = gk[i];
      bf16x8 v8 = gv[i];
      int tc = row >> 3, tb = (row & 7) << 1, xr = ch & 3;
#pragma unroll
      for (int e = 0; e < 8; ++e) {
        int d = ch * 8 + e;
        *(__bf16*)(smem + VT_O + d * 208 + ((tc ^ xr) << 4) + tb) = v8[e];
      }
    }
  }
  __syncthreads();

  int ljv[6]; bool cok[6];
#pragma unroll
  for (int j = 0; j < 6; ++j) {
    int col = j * 16 + r16;
    ljv[j] = mod29(col);
    cok[j] = col < 87;
  }

  for (int m = wave; m < 6; m += 4) {
    f32x4 s[6] = {};
#pragma unroll
    for (int kk = 0; kk < 2; ++kk) {
      bf16x8 aq = *(const bf16x8*)(smem + QS_O + (m * 16 + r16) * 144 + kk * 64 + r4 * 16);
#pragma unroll
      for (int j = 0; j < 6; ++j) {
        bf16x8 kb = *(const bf16x8*)(smem + KS_O + (j * 16 + r16) * 144 + kk * 64 + r4 * 16);
        s[j] = __builtin_amdgcn_mfma_f32_16x16x32_bf16(aq, kb, s[j], 0, 0, 0);
      }
    }
#pragma unroll
    for (int rr = 0; rr < 4; ++rr) {
      int row = m * 16 + r4 * 4 + rr;
      bool rok = row < 87;
      int lr = mod29(row);
      float mxv = -1e30f;
#pragma unroll
      for (int j = 0; j < 6; ++j) {
        bool al = rok && cok[j] && (ljv[j] <= lr) && (ljv[j] + 21 >= lr);
        float sv = al ? s[j][rr] * 0.125f : -1e30f;
        s[j][rr] = sv;
        mxv = fmaxf(mxv, sv);
      }
      mxv = fmaxf(mxv, __shfl_xor(mxv, 1));
      mxv = fmaxf(mxv, __shfl_xor(mxv, 2));
      mxv = fmaxf(mxv, __shfl_xor(mxv, 4));
      mxv = fmaxf(mxv, __shfl_xor(mxv, 8));
      float sm = 0.f;
#pragma unroll
      for (int j = 0; j < 6; ++j) {
        float e = __expf(s[j][rr] - mxv);
        s[j][rr] = e;
        sm += e;
      }
      sm += __shfl_xor(sm, 1);
      sm += __shfl_xor(sm, 2);
      sm += __shfl_xor(sm, 4);
      sm += __shfl_xor(sm, 8);
      float inv = rok ? 1.f / sm : 0.f;
#pragma unroll
      for (int j = 0; j < 6; ++j)
        *(__hip_bfloat16*)(smem + PB_O + row * 208 + (j * 16 + r16) * 2) =
            __float2bfloat16(s[j][rr] * inv);
    }
  }
  __syncthreads();

  for (int p = 0; p < 6; ++p) {
    int pair = wave + p * 4;
    int mt = pair >> 2, nt = pair & 3;
    int d = nt * 16 + r16;
    int dx = (d >> 3) & 3;
    f32x4 acc = {0.f, 0.f, 0.f, 0.f};
#pragma unroll
    for (int kk = 0; kk < 3; ++kk) {
      bf16x8 a  = *(const bf16x8*)(smem + PB_O + (mt * 16 + r16) * 208 + kk * 64 + r4 * 16);
      bf16x8 bb = *(const bf16x8*)(smem + VT_O + d * 208 + (((kk * 4 + r4) ^ dx) << 4));
      acc = __builtin_amdgcn_mfma_f32_16x16x32_bf16(a, bb, acc, 0, 0, 0);
    }
    int t0 = mt * 16 + r4 * 4;
#pragma unroll
    for (int r = 0; r < 4; ++r)
      *(__bf16*)(smem + QS_O + (t0 + r) * 136 + d * 2) =
          __builtin_bit_cast(__bf16, __builtin_bit_cast(unsigned short, __float2bfloat16(acc[r])));
  }
  __syncthreads();

  for (int i = tid; i < 768; i += 256) {
    int row = i >> 3, ch = i & 7;
    if (row < 87) {
      bf16x8 vrow = *(const bf16x8*)(smem + QS_O + row * 136 + ch * 16);
      *(bf16x8*)((char*)y_ws + ((size_t)b * 87 + row) * 1024 + h * 128 + ch * 16) = vrow;
    }
  }
}

// ---------------- launch ----------------
extern "C" void kernel_launch(void* const* d_in, const int* in_sizes, int n_in,
                              void* d_out, int out_size, void* d_ws, size_t ws_size,
                              hipStream_t stream) {
  const float* x  = (const float*)d_in[0];
  const float* Wq = (const float*)d_in[1];
  const float* bq = (const float*)d_in[2];
  const float* Wk = (const float*)d_in[3];
  const float* bk = (const float*)d_in[4];
  const float* Wv = (const float*)d_in[5];
  const float* bv = (const float*)d_in[6];
  const float* Wp = (const float*)d_in[7];
  const float* bp = (const float*)d_in[8];
  float* out = (float*)d_out;

  char* ws = (char*)d_ws;
  size_t off = 0;
  __hip_bfloat16* xb    = (__hip_bfloat16*)(ws + off); off += (size_t)BT_ * 512 * 2;
  __hip_bfloat16* wqkv  = (__hip_bfloat16*)(ws + off); off += 1536 * 512 * 2;
  __hip_bfloat16* wp    = (__hip_bfloat16*)(ws + off); off += 512 * 512 * 2;
  float*          biasc = (float*)(ws + off);          off += 8192;
  __hip_bfloat16* q_ws  = (__hip_bfloat16*)(ws + off); off += (size_t)BH_ * 6144 * 2;
  __hip_bfloat16* k_ws  = (__hip_bfloat16*)(ws + off); off += (size_t)BH_ * 6144 * 2;
  __hip_bfloat16* v_ws  = (__hip_bfloat16*)(ws + off); off += (size_t)BH_ * 6144 * 2;
  __hip_bfloat16* yb = xb;  // alias: xb fully consumed by qkv before attn writes y

  if (ws_size < off) return;

  convert_x_kernel<<<2048, 256, 0, stream>>>(x, xb, BT_ * 512 / 4);
  convert_w_kernel<<<1024, 256, 0, stream>>>(Wq, Wk, Wv, Wp, bq, bk, bv, wqkv, wp, biasc);
  // qkv: 256x128 tiles -> 174 x 12 = 2088 blocks (div by 8)
  gemmk_kernel<0><<<2088, 256, 0, stream>>>(xb, wqkv, biasc, 12, q_ws, k_ws, v_ws);
  attn_kernel<<<BH_, 256, 0, stream>>>(q_ws, k_ws, v_ws, yb);
  // proj: 256x128 tiles -> 174 x 4 = 696 blocks (div by 8)
  gemmk_kernel<1><<<696, 256, 0, stream>>>(yb, wp, bp, 4, out, nullptr, nullptr);
}

// Round 17
// 239.479 us; speedup vs baseline: 1.1468x; 1.1468x over previous
//
#include <hip/hip_runtime.h>
#include <hip/hip_bf16.h>
#include <stdint.h>

// Problem constants
#define B_   512
#define T_   87
#define C_   512
#define H_   8
#define D_   64
#define BT_  44544        // B_*T_
#define BH_  4096         // B_*H_

typedef __attribute__((ext_vector_type(4))) float f32x4;
typedef __attribute__((ext_vector_type(8))) __bf16 bf16x8;
typedef __attribute__((ext_vector_type(4))) unsigned short u16x4;

__device__ __forceinline__ int mod29(int x) {
  return x < 29 ? x : (x < 58 ? x - 29 : x - 58);
}

// ---------------- converts ----------------

__global__ void convert_x_kernel(const float* __restrict__ x,
                                 __hip_bfloat16* __restrict__ xb, int n4) {
  int stride = gridDim.x * blockDim.x;
  for (int i = blockIdx.x * blockDim.x + threadIdx.x; i < n4; i += stride) {
    f32x4 v = ((const f32x4*)x)[i];
    u16x4 o;
    o.x = __builtin_bit_cast(unsigned short, __float2bfloat16(v.x));
    o.y = __builtin_bit_cast(unsigned short, __float2bfloat16(v.y));
    o.z = __builtin_bit_cast(unsigned short, __float2bfloat16(v.z));
    o.w = __builtin_bit_cast(unsigned short, __float2bfloat16(v.w));
    ((u16x4*)xb)[i] = o;
  }
}

__global__ void convert_w_kernel(const float* __restrict__ Wq, const float* __restrict__ Wk,
                                 const float* __restrict__ Wv, const float* __restrict__ Wp,
                                 const float* __restrict__ bq, const float* __restrict__ bk,
                                 const float* __restrict__ bv,
                                 __hip_bfloat16* __restrict__ wqkv,
                                 __hip_bfloat16* __restrict__ wp,
                                 float* __restrict__ biasc) {
  const int NW = 262144;                 // 512*512
  const int total = 3 * NW + NW + 1536;
  int stride = gridDim.x * blockDim.x;
  for (int i = blockIdx.x * blockDim.x + threadIdx.x; i < total; i += stride) {
    if (i < 3 * NW) {
      float v = (i < NW) ? Wq[i] : (i < 2 * NW ? Wk[i - NW] : Wv[i - 2 * NW]);
      wqkv[i] = __float2bfloat16(v);
    } else if (i < 4 * NW) {
      wp[i - 3 * NW] = __float2bfloat16(Wp[i - 3 * NW]);
    } else {
      int j = i - 4 * NW;
      biasc[j] = (j < 512) ? bq[j] : (j < 1024 ? bk[j - 512] : bv[j - 1024]);
    }
  }
}

// ---------------- gemms: 128x128 tile, BK=32, 4 waves, 32KB LDS -> 4 blk/CU --
// 64B rows = 4 x 16B chunks; LDS chunk s of row r holds global chunk
// s^((r>>1)&3) (R5-verified swizzle -> ~2-way bank aliasing, free).
// Depth-1 reg staging (R7-verified): load kt+1 to regs, compute kt, write, sync.

// EPI 0: qkv row-major outputs (o0=q,o1=k,o2=v, bias=biasc). EPI 1: proj fp32.
template<int EPI>
__global__ __launch_bounds__(256, 4) void gemms_kernel(
    const __hip_bfloat16* __restrict__ A, const __hip_bfloat16* __restrict__ Bt,
    const float* __restrict__ bias, int ntn,
    void* __restrict__ o0, void* __restrict__ o1, void* __restrict__ o2) {
  __shared__ __align__(16) char smem[2][2][8192];  // [buf][A|B][128 rows x 64B]

  int tid = threadIdx.x, lane = tid & 63, wave = tid >> 6;
  int r16 = lane & 15, r4 = lane >> 4;

  int nwg = gridDim.x;
  int wg = (blockIdx.x & 7) * (nwg >> 3) + (blockIdx.x >> 3);
  int tileM = (wg / ntn) * 128, tileN = (wg % ntn) * 128;

  int wr = wave >> 1, wc = wave & 1;       // per-wave 64x64
  int wbM = wr * 64, wbN = wc * 64;

  // staging geometry: thread covers rows rl, rl+64 ; 16B chunk c
  const int rl = tid >> 2, c = tid & 3;
  const char* Ag = (const char*)A + (size_t)(tileM + rl) * 1024 + c * 16;
  const char* Bg = (const char*)Bt + (size_t)(tileN + rl) * 1024 + c * 16;
  int lsl[2];                              // LDS byte slot per j (row-dependent swz)
#pragma unroll
  for (int j = 0; j < 2; ++j) {
    int row = rl + 64 * j;
    lsl[j] = row * 64 + ((c ^ ((row >> 1) & 3)) << 4);
  }

  // ds_read row/addr constants
  int aoff[4], boff[4];
#pragma unroll
  for (int f = 0; f < 4; ++f) {
    int ra = wbM + f * 16 + r16;
    int rb = wbN + f * 16 + r16;
    aoff[f] = ra * 64 + ((r4 ^ ((ra >> 1) & 3)) << 4);
    boff[f] = rb * 64 + ((r4 ^ ((rb >> 1) & 3)) << 4);
  }

  f32x4 acc[4][4] = {};
  bf16x8 sA[2], sB[2];

  // prologue: tile 0 -> regs -> LDS buf0
#pragma unroll
  for (int j = 0; j < 2; ++j) {
    sA[j] = *(const bf16x8*)(Ag + (size_t)j * 65536);
    sB[j] = *(const bf16x8*)(Bg + (size_t)j * 65536);
  }
#pragma unroll
  for (int j = 0; j < 2; ++j) {
    *(bf16x8*)(&smem[0][0][0] + lsl[j]) = sA[j];
    *(bf16x8*)(&smem[0][1][0] + lsl[j]) = sB[j];
  }
  __syncthreads();

#pragma unroll
  for (int kt = 0; kt < 16; ++kt) {
    const int cur = kt & 1;
    if (kt < 15) {
#pragma unroll
      for (int j = 0; j < 2; ++j) {
        sA[j] = *(const bf16x8*)(Ag + (size_t)j * 65536 + (kt + 1) * 64);
        sB[j] = *(const bf16x8*)(Bg + (size_t)j * 65536 + (kt + 1) * 64);
      }
    }
    {
      const char* Ab = &smem[cur][0][0];
      const char* Bb = &smem[cur][1][0];
      bf16x8 bfr[4];
#pragma unroll
      for (int fn = 0; fn < 4; ++fn) bfr[fn] = *(const bf16x8*)(Bb + boff[fn]);
      __builtin_amdgcn_s_setprio(1);
#pragma unroll
      for (int fm = 0; fm < 4; ++fm) {
        bf16x8 a = *(const bf16x8*)(Ab + aoff[fm]);
#pragma unroll
        for (int fn = 0; fn < 4; ++fn)
          acc[fm][fn] = __builtin_amdgcn_mfma_f32_16x16x32_bf16(a, bfr[fn],
                                                                acc[fm][fn], 0, 0, 0);
      }
      __builtin_amdgcn_s_setprio(0);
    }
    if (kt < 15) {
#pragma unroll
      for (int j = 0; j < 2; ++j) {
        *(bf16x8*)(&smem[cur ^ 1][0][0] + lsl[j]) = sA[j];
        *(bf16x8*)(&smem[cur ^ 1][1][0] + lsl[j]) = sB[j];
      }
    }
    __syncthreads();
  }

  // ---- bounce epilogue (R10-verified): frag -> LDS scratch -> coalesced ----
  if constexpr (EPI == 0) {
    char* scratch = &smem[0][0][0] + wave * 2304;      // 16 rows x 144B
    int gn0 = tileN + wbN;                             // head-aligned (64 | gn0)
    int sel = gn0 >> 9;                                // 0=q 1=k 2=v
    int hh = (gn0 & 511) >> 6;
    __hip_bfloat16* obase = (sel == 0) ? (__hip_bfloat16*)o0
                          : (sel == 1) ? (__hip_bfloat16*)o1 : (__hip_bfloat16*)o2;
#pragma unroll
    for (int fm = 0; fm < 4; ++fm) {
#pragma unroll
      for (int fn = 0; fn < 4; ++fn) {
        float bv = bias[gn0 + fn * 16 + r16];
#pragma unroll
        for (int rr = 0; rr < 4; ++rr)
          *(__hip_bfloat16*)(scratch + (r4 * 4 + rr) * 144 + (fn * 16 + r16) * 2) =
              __float2bfloat16(acc[fm][fn][rr] + bv);
      }
#pragma unroll
      for (int p = 0; p < 2; ++p) {
        bf16x8 vrow = *(const bf16x8*)(scratch + (p * 8 + (lane >> 3)) * 144 + (lane & 7) * 16);
        int gm = tileM + wbM + fm * 16 + p * 8 + (lane >> 3);
        int bb = gm / 87, tt = gm - bb * 87;
        *(bf16x8*)(obase + ((size_t)(bb * 8 + hh) * 96 + tt) * 64 + (lane & 7) * 8) = vrow;
      }
    }
  } else {
    char* scratch = &smem[0][0][0] + wave * 4352;      // 16 rows x 272B
#pragma unroll
    for (int fm = 0; fm < 4; ++fm) {
#pragma unroll
      for (int fn = 0; fn < 4; ++fn) {
        float bv = bias[tileN + wbN + fn * 16 + r16];
#pragma unroll
        for (int rr = 0; rr < 4; ++rr)
          *(float*)(scratch + (r4 * 4 + rr) * 272 + (fn * 16 + r16) * 4) =
              acc[fm][fn][rr] + bv;
      }
#pragma unroll
      for (int p = 0; p < 4; ++p) {
        f32x4 vr = *(const f32x4*)(scratch + (p * 4 + (lane >> 4)) * 272 + (lane & 15) * 16);
        int gm = tileM + wbM + fm * 16 + p * 4 + (lane >> 4);
        *(f32x4*)((float*)o0 + (size_t)gm * 512 + tileN + wbN + (lane & 15) * 4) = vr;
      }
    }
  }
}

// ---------------- attention per (b,h) (R12-verified, y-bounce) ---------------
#define QS_O  0
#define KS_O  13824
#define VT_O  27648
#define PB_O  40960

__global__ __launch_bounds__(256) void attn_kernel(
    const __hip_bfloat16* __restrict__ q_ws, const __hip_bfloat16* __restrict__ k_ws,
    const __hip_bfloat16* __restrict__ v_ws, __hip_bfloat16* __restrict__ y_ws) {
  __shared__ __align__(16) char smem[60928];

  int tid = threadIdx.x, lane = tid & 63, wave = tid >> 6;
  int bh = blockIdx.x, b = bh >> 3, h = bh & 7;
  int r16 = lane & 15, r4 = lane >> 4;

  {
    const bf16x8* gq = (const bf16x8*)(q_ws + (size_t)bh * 6144);
    const bf16x8* gk = (const bf16x8*)(k_ws + (size_t)bh * 6144);
    const bf16x8* gv = (const bf16x8*)(v_ws + (size_t)bh * 6144);
    for (int i = tid; i < 768; i += 256) {
      int row = i >> 3, ch = i & 7;
      *(bf16x8*)(smem + QS_O + row * 144 + ch * 16) = gq[i];
      *(bf16x8*)(smem + KS_O + row * 144 + ch * 16) = gk[i];
      bf16x8 v8 = gv[i];
      int tc = row >> 3, tb = (row & 7) << 1, xr = ch & 3;
#pragma unroll
      for (int e = 0; e < 8; ++e) {
        int d = ch * 8 + e;
        *(__bf16*)(smem + VT_O + d * 208 + ((tc ^ xr) << 4) + tb) = v8[e];
      }
    }
  }
  __syncthreads();

  int ljv[6]; bool cok[6];
#pragma unroll
  for (int j = 0; j < 6; ++j) {
    int col = j * 16 + r16;
    ljv[j] = mod29(col);
    cok[j] = col < 87;
  }

  for (int m = wave; m < 6; m += 4) {
    f32x4 s[6] = {};
#pragma unroll
    for (int kk = 0; kk < 2; ++kk) {
      bf16x8 aq = *(const bf16x8*)(smem + QS_O + (m * 16 + r16) * 144 + kk * 64 + r4 * 16);
#pragma unroll
      for (int j = 0; j < 6; ++j) {
        bf16x8 kb = *(const bf16x8*)(smem + KS_O + (j * 16 + r16) * 144 + kk * 64 + r4 * 16);
        s[j] = __builtin_amdgcn_mfma_f32_16x16x32_bf16(aq, kb, s[j], 0, 0, 0);
      }
    }
#pragma unroll
    for (int rr = 0; rr < 4; ++rr) {
      int row = m * 16 + r4 * 4 + rr;
      bool rok = row < 87;
      int lr = mod29(row);
      float mxv = -1e30f;
#pragma unroll
      for (int j = 0; j < 6; ++j) {
        bool al = rok && cok[j] && (ljv[j] <= lr) && (ljv[j] + 21 >= lr);
        float sv = al ? s[j][rr] * 0.125f : -1e30f;
        s[j][rr] = sv;
        mxv = fmaxf(mxv, sv);
      }
      mxv = fmaxf(mxv, __shfl_xor(mxv, 1));
      mxv = fmaxf(mxv, __shfl_xor(mxv, 2));
      mxv = fmaxf(mxv, __shfl_xor(mxv, 4));
      mxv = fmaxf(mxv, __shfl_xor(mxv, 8));
      float sm = 0.f;
#pragma unroll
      for (int j = 0; j < 6; ++j) {
        float e = __expf(s[j][rr] - mxv);
        s[j][rr] = e;
        sm += e;
      }
      sm += __shfl_xor(sm, 1);
      sm += __shfl_xor(sm, 2);
      sm += __shfl_xor(sm, 4);
      sm += __shfl_xor(sm, 8);
      float inv = rok ? 1.f / sm : 0.f;
#pragma unroll
      for (int j = 0; j < 6; ++j)
        *(__hip_bfloat16*)(smem + PB_O + row * 208 + (j * 16 + r16) * 2) =
            __float2bfloat16(s[j][rr] * inv);
    }
  }
  __syncthreads();

  for (int p = 0; p < 6; ++p) {
    int pair = wave + p * 4;
    int mt = pair >> 2, nt = pair & 3;
    int d = nt * 16 + r16;
    int dx = (d >> 3) & 3;
    f32x4 acc = {0.f, 0.f, 0.f, 0.f};
#pragma unroll
    for (int kk = 0; kk < 3; ++kk) {
      bf16x8 a  = *(const bf16x8*)(smem + PB_O + (mt * 16 + r16) * 208 + kk * 64 + r4 * 16);
      bf16x8 bb = *(const bf16x8*)(smem + VT_O + d * 208 + (((kk * 4 + r4) ^ dx) << 4));
      acc = __builtin_amdgcn_mfma_f32_16x16x32_bf16(a, bb, acc, 0, 0, 0);
    }
    int t0 = mt * 16 + r4 * 4;
#pragma unroll
    for (int r = 0; r < 4; ++r)
      *(__bf16*)(smem + QS_O + (t0 + r) * 136 + d * 2) =
          __builtin_bit_cast(__bf16, __builtin_bit_cast(unsigned short, __float2bfloat16(acc[r])));
  }
  __syncthreads();

  for (int i = tid; i < 768; i += 256) {
    int row = i >> 3, ch = i & 7;
    if (row < 87) {
      bf16x8 vrow = *(const bf16x8*)(smem + QS_O + row * 136 + ch * 16);
      *(bf16x8*)((char*)y_ws + ((size_t)b * 87 + row) * 1024 + h * 128 + ch * 16) = vrow;
    }
  }
}

// ---------------- launch ----------------
extern "C" void kernel_launch(void* const* d_in, const int* in_sizes, int n_in,
                              void* d_out, int out_size, void* d_ws, size_t ws_size,
                              hipStream_t stream) {
  const float* x  = (const float*)d_in[0];
  const float* Wq = (const float*)d_in[1];
  const float* bq = (const float*)d_in[2];
  const float* Wk = (const float*)d_in[3];
  const float* bk = (const float*)d_in[4];
  const float* Wv = (const float*)d_in[5];
  const float* bv = (const float*)d_in[6];
  const float* Wp = (const float*)d_in[7];
  const float* bp = (const float*)d_in[8];
  float* out = (float*)d_out;

  char* ws = (char*)d_ws;
  size_t off = 0;
  __hip_bfloat16* xb    = (__hip_bfloat16*)(ws + off); off += (size_t)BT_ * 512 * 2;
  __hip_bfloat16* wqkv  = (__hip_bfloat16*)(ws + off); off += 1536 * 512 * 2;
  __hip_bfloat16* wp    = (__hip_bfloat16*)(ws + off); off += 512 * 512 * 2;
  float*          biasc = (float*)(ws + off);          off += 8192;
  __hip_bfloat16* q_ws  = (__hip_bfloat16*)(ws + off); off += (size_t)BH_ * 6144 * 2;
  __hip_bfloat16* k_ws  = (__hip_bfloat16*)(ws + off); off += (size_t)BH_ * 6144 * 2;
  __hip_bfloat16* v_ws  = (__hip_bfloat16*)(ws + off); off += (size_t)BH_ * 6144 * 2;
  __hip_bfloat16* yb = xb;  // alias: xb fully consumed by qkv before attn writes y

  if (ws_size < off) return;

  convert_x_kernel<<<2048, 256, 0, stream>>>(x, xb, BT_ * 512 / 4);
  convert_w_kernel<<<1024, 256, 0, stream>>>(Wq, Wk, Wv, Wp, bq, bk, bv, wqkv, wp, biasc);
  // qkv: 128x128 tiles -> 348 x 12 = 4176 blocks (div by 8)
  gemms_kernel<0><<<4176, 256, 0, stream>>>(xb, wqkv, biasc, 12, q_ws, k_ws, v_ws);
  attn_kernel<<<BH_, 256, 0, stream>>>(q_ws, k_ws, v_ws, yb);
  // proj: 128x128 tiles -> 348 x 4 = 1392 blocks (div by 8)
  gemms_kernel<1><<<1392, 256, 0, stream>>>(yb, wp, bp, 4, out, nullptr, nullptr);
}